// Round 1
// baseline (8977.879 us; speedup 1.0000x reference)
//
#include <hip/hip_runtime.h>
#include <math.h>

// WanModel transformer block, fp32 baseline (correctness-first).
// L=4032 (9*16*28), C=1536, NH=12, D=128, L2=512, FFN=8960.
// Future rounds: bf16 MFMA GEMMs + MFMA attention.

#define L_SEQ 4032
#define C_DIM 1536
#define L_CTX 512
#define FFN_DIM 8960
#define NHEAD 12
#define DHEAD 128
#define FFN_CHUNK 1344  // 21*64, L_SEQ = 3*1344

// ---------------- block-wide reduction (256 threads = 4 waves) --------------
__device__ inline float2 block_sum2(float2 v) {
  __shared__ float2 red[4];
#pragma unroll
  for (int o = 32; o > 0; o >>= 1) {
    v.x += __shfl_xor(v.x, o, 64);
    v.y += __shfl_xor(v.y, o, 64);
  }
  int wave = threadIdx.x >> 6;
  if ((threadIdx.x & 63) == 0) red[wave] = v;
  __syncthreads();
  float2 t = make_float2(0.f, 0.f);
#pragma unroll
  for (int i = 0; i < 4; ++i) { t.x += red[i].x; t.y += red[i].y; }
  return t;
}

// ---------------- small elementwise kernels --------------------------------
__global__ void add_kernel(float* __restrict__ o, const float* __restrict__ a,
                           const float* __restrict__ b, int n) {
  int i = blockIdx.x * 256 + threadIdx.x;
  if (i < n) o[i] = a[i] + b[i];
}

// out = x + y * gate[channel]   (float4, n % (4*256) == 0 handled by exact grid)
__global__ void resid_gate_kernel(float* __restrict__ o, const float* __restrict__ x,
                                  const float* __restrict__ y, const float* __restrict__ g,
                                  int n) {
  int i = (blockIdx.x * 256 + threadIdx.x) * 4;
  if (i < n) {
    float4 xv = *(const float4*)&x[i];
    float4 yv = *(const float4*)&y[i];
    float4 gv = *(const float4*)&g[i % C_DIM];
    float4 ov;
    ov.x = xv.x + yv.x * gv.x;
    ov.y = xv.y + yv.y * gv.y;
    ov.z = xv.z + yv.z * gv.z;
    ov.w = xv.w + yv.w * gv.w;
    *(float4*)&o[i] = ov;
  }
}

__global__ void resid_kernel(float* __restrict__ o, const float* __restrict__ x,
                             const float* __restrict__ y, int n) {
  int i = (blockIdx.x * 256 + threadIdx.x) * 4;
  if (i < n) {
    float4 xv = *(const float4*)&x[i];
    float4 yv = *(const float4*)&y[i];
    float4 ov;
    ov.x = xv.x + yv.x; ov.y = xv.y + yv.y; ov.z = xv.z + yv.z; ov.w = xv.w + yv.w;
    *(float4*)&o[i] = ov;
  }
}

// ---------------- LayerNorm with affine (scale = addOne + sc[c]) -----------
__global__ __launch_bounds__(256) void ln_affine_kernel(
    float* __restrict__ out, const float* __restrict__ in,
    const float* __restrict__ sc, const float* __restrict__ sh,
    float addOne) {
  int row = blockIdx.x;
  const float* xr = in + (size_t)row * C_DIM;
  float vals[C_DIM / 256];
  float2 p = make_float2(0.f, 0.f);
  int cnt = 0;
  for (int c = threadIdx.x; c < C_DIM; c += 256) {
    float v = xr[c];
    vals[cnt++] = v;
    p.x += v; p.y += v * v;
  }
  float2 t = block_sum2(p);
  float mean = t.x * (1.f / C_DIM);
  float var = t.y * (1.f / C_DIM) - mean * mean;
  float r = rsqrtf(var + 1e-6f);
  cnt = 0;
  for (int c = threadIdx.x; c < C_DIM; c += 256) {
    float xh = (vals[cnt++] - mean) * r;
    out[(size_t)row * C_DIM + c] = xh * (addOne + sc[c]) + sh[c];
  }
}

// ---------------- RMS norm over full C, in-place ---------------------------
__global__ __launch_bounds__(256) void rms_kernel(float* io, const float* __restrict__ w,
                                                  int rows_unused) {
  int row = blockIdx.x;
  float* xr = io + (size_t)row * C_DIM;
  float vals[C_DIM / 256];
  float s2 = 0.f;
  int cnt = 0;
  for (int c = threadIdx.x; c < C_DIM; c += 256) {
    float v = xr[c];
    vals[cnt++] = v;
    s2 += v * v;
  }
  float2 t = block_sum2(make_float2(s2, 0.f));
  float r = rsqrtf(t.x * (1.f / C_DIM) + 1e-6f);
  cnt = 0;
  for (int c = threadIdx.x; c < C_DIM; c += 256) {
    xr[c] = vals[cnt++] * r * w[c];
  }
}

// ---------------- RoPE tables (f64 to match numpy) -------------------------
__global__ void rope_tables_kernel(float* __restrict__ cosb, float* __restrict__ sinb) {
  int l = blockIdx.x, j = threadIdx.x;  // 64 threads
  int f = l / (16 * 28);
  int rem = l % (16 * 28);
  int hh = rem / 28, ww = rem % 28;
  double inv = pow(10000.0, -(double)(2 * j) / 128.0);
  double pos = (j < 22) ? (double)f : ((j < 43) ? (double)hh : (double)ww);
  double ang = pos * inv;
  cosb[l * 64 + j] = (float)cos(ang);
  sinb[l * 64 + j] = (float)sin(ang);
}

__global__ void rope_apply_kernel(float* __restrict__ x, const float* __restrict__ cosb,
                                  const float* __restrict__ sinb) {
  int l = blockIdx.x;
  for (int t = threadIdx.x; t < NHEAD * 64; t += 256) {
    int n = t >> 6, j = t & 63;
    float co = cosb[l * 64 + j], si = sinb[l * 64 + j];
    float* p = x + (size_t)l * C_DIM + n * DHEAD + 2 * j;
    float x0 = p[0], x1 = p[1];
    p[0] = x0 * co - x1 * si;
    p[1] = x0 * si + x1 * co;
  }
}

// ---------------- fp32 tiled GEMM: C = A(MxK) @ W(KxN) + bias --------------
// M%64==0, N%64==0, K%16==0. EPI: 0=none, 1=tanh-gelu.
__device__ inline float gelu_tanh(float x) {
  float x3 = x * x * x;
  return 0.5f * x * (1.f + tanhf(0.79788456080286535588f * (x + 0.044715f * x3)));
}

template <int EPI>
__global__ __launch_bounds__(256) void gemm_kernel(
    const float* __restrict__ A, const float* __restrict__ W,
    const float* __restrict__ bias, float* __restrict__ Co,
    int M, int N, int K) {
  __shared__ float As[16][64];
  __shared__ float Bs[16][64];
  const int tid = threadIdx.x;
  const int tx = tid & 15, ty = tid >> 4;
  const int row0 = blockIdx.y * 64, col0 = blockIdx.x * 64;
  const int lm = tid >> 2, lk = (tid & 3) << 2;   // A tile: 64 rows x 16 k
  const int bk = tid >> 4, bn = (tid & 15) << 2;  // B tile: 16 k x 64 cols
  float acc[4][4] = {};
  const float* Aptr = A + (size_t)(row0 + lm) * K + lk;
  const float* Wp = W + (size_t)bk * N + col0 + bn;
  for (int k0 = 0; k0 < K; k0 += 16) {
    float4 a4 = *(const float4*)(Aptr + k0);
    float4 b4 = *(const float4*)(Wp + (size_t)k0 * N);
    __syncthreads();
    As[lk + 0][lm] = a4.x; As[lk + 1][lm] = a4.y;
    As[lk + 2][lm] = a4.z; As[lk + 3][lm] = a4.w;
    *(float4*)&Bs[bk][bn] = b4;
    __syncthreads();
#pragma unroll
    for (int k = 0; k < 16; ++k) {
      float4 av = *(const float4*)&As[k][ty << 2];
      float4 bv = *(const float4*)&Bs[k][tx << 2];
      float am[4] = {av.x, av.y, av.z, av.w};
      float bm[4] = {bv.x, bv.y, bv.z, bv.w};
#pragma unroll
      for (int i = 0; i < 4; ++i)
#pragma unroll
        for (int j = 0; j < 4; ++j) acc[i][j] = fmaf(am[i], bm[j], acc[i][j]);
    }
  }
  float4 bv4 = *(const float4*)&bias[col0 + (tx << 2)];
#pragma unroll
  for (int i = 0; i < 4; ++i) {
    float o0 = acc[i][0] + bv4.x;
    float o1 = acc[i][1] + bv4.y;
    float o2 = acc[i][2] + bv4.z;
    float o3 = acc[i][3] + bv4.w;
    if (EPI == 1) { o0 = gelu_tanh(o0); o1 = gelu_tanh(o1); o2 = gelu_tanh(o2); o3 = gelu_tanh(o3); }
    float4 ov = {o0, o1, o2, o3};
    *(float4*)&Co[(size_t)(row0 + (ty << 2) + i) * N + col0 + (tx << 2)] = ov;
  }
}

// ---------------- fp32 flash attention -------------------------------------
// Q,K,V,O layout: (rows, C_DIM) with head h at cols [h*128, h*128+128).
// Grid: (Lq/32, NHEAD). Block: 256. Online softmax, key chunks of 32.
__global__ __launch_bounds__(256) void attn_kernel(
    const float* __restrict__ Q, const float* __restrict__ Kb,
    const float* __restrict__ Vb, float* __restrict__ O, int Lk) {
  const int h = blockIdx.y;
  const int q0 = blockIdx.x * 32;
  const int tid = threadIdx.x;
  __shared__ float Qs[32][132];  // +4 pad keeps float4 alignment, breaks bank aliasing
  __shared__ float Ks[32][132];
  __shared__ float Vs[32][132];
  const float scale = 0.08838834764831845f;  // 1/sqrt(128)

#pragma unroll
  for (int i = 0; i < 4; ++i) {
    int idx = tid * 16 + i * 4;
    int r = idx >> 7, c = idx & 127;
    float4 v = *(const float4*)&Q[(size_t)(q0 + r) * C_DIM + h * DHEAD + c];
    v.x *= scale; v.y *= scale; v.z *= scale; v.w *= scale;
    *(float4*)&Qs[r][c] = v;
  }
  const int qi = tid >> 3;          // query row (0..31), 8 lanes per row
  const int g8 = tid & 7;           // position within the 8-lane row group
  const int d0 = g8 << 4;           // 16 output dims owned by this thread
  float acc[16];
#pragma unroll
  for (int j = 0; j < 16; ++j) acc[j] = 0.f;
  float m_reg = -1e30f, l_reg = 0.f;

  for (int k0 = 0; k0 < Lk; k0 += 32) {
    __syncthreads();  // prev-iter LDS reads done
#pragma unroll
    for (int i = 0; i < 4; ++i) {
      int idx = tid * 16 + i * 4;
      int r = idx >> 7, c = idx & 127;
      *(float4*)&Ks[r][c] = *(const float4*)&Kb[(size_t)(k0 + r) * C_DIM + h * DHEAD + c];
      *(float4*)&Vs[r][c] = *(const float4*)&Vb[(size_t)(k0 + r) * C_DIM + h * DHEAD + c];
    }
    __syncthreads();
    // scores: this thread covers keys kj = g8 + 8*i (i=0..3) for query qi
    float s[4] = {0.f, 0.f, 0.f, 0.f};
#pragma unroll
    for (int dd = 0; dd < 32; ++dd) {
      float4 q4 = *(const float4*)&Qs[qi][dd << 2];
#pragma unroll
      for (int i = 0; i < 4; ++i) {
        float4 k4 = *(const float4*)&Ks[g8 + (i << 3)][dd << 2];
        s[i] += q4.x * k4.x + q4.y * k4.y + q4.z * k4.z + q4.w * k4.w;
      }
    }
    float lmax = fmaxf(fmaxf(s[0], s[1]), fmaxf(s[2], s[3]));
#pragma unroll
    for (int o = 1; o < 8; o <<= 1) lmax = fmaxf(lmax, __shfl_xor(lmax, o, 8));
    float m_new = fmaxf(m_reg, lmax);
    float alpha = expf(m_reg - m_new);
    float p[4], ps = 0.f;
#pragma unroll
    for (int i = 0; i < 4; ++i) { p[i] = expf(s[i] - m_new); ps += p[i]; }
#pragma unroll
    for (int o = 1; o < 8; o <<= 1) ps += __shfl_xor(ps, o, 8);
    l_reg = l_reg * alpha + ps;
    m_reg = m_new;
#pragma unroll
    for (int j = 0; j < 16; ++j) acc[j] *= alpha;
    // PV: p for key kj lives in lane (kj&7) of this row group, slot kj>>3
#pragma unroll
    for (int i = 0; i < 4; ++i) {
#pragma unroll
      for (int g = 0; g < 8; ++g) {
        int kj = (i << 3) + g;
        float pk = __shfl(p[i], g, 8);
        float4 v0 = *(const float4*)&Vs[kj][d0];
        float4 v1 = *(const float4*)&Vs[kj][d0 + 4];
        float4 v2 = *(const float4*)&Vs[kj][d0 + 8];
        float4 v3 = *(const float4*)&Vs[kj][d0 + 12];
        acc[0]  = fmaf(pk, v0.x, acc[0]);  acc[1]  = fmaf(pk, v0.y, acc[1]);
        acc[2]  = fmaf(pk, v0.z, acc[2]);  acc[3]  = fmaf(pk, v0.w, acc[3]);
        acc[4]  = fmaf(pk, v1.x, acc[4]);  acc[5]  = fmaf(pk, v1.y, acc[5]);
        acc[6]  = fmaf(pk, v1.z, acc[6]);  acc[7]  = fmaf(pk, v1.w, acc[7]);
        acc[8]  = fmaf(pk, v2.x, acc[8]);  acc[9]  = fmaf(pk, v2.y, acc[9]);
        acc[10] = fmaf(pk, v2.z, acc[10]); acc[11] = fmaf(pk, v2.w, acc[11]);
        acc[12] = fmaf(pk, v3.x, acc[12]); acc[13] = fmaf(pk, v3.y, acc[13]);
        acc[14] = fmaf(pk, v3.z, acc[14]); acc[15] = fmaf(pk, v3.w, acc[15]);
      }
    }
  }
  float invl = 1.f / l_reg;
#pragma unroll
  for (int jj = 0; jj < 4; ++jj) {
    float4 ov = {acc[jj * 4 + 0] * invl, acc[jj * 4 + 1] * invl,
                 acc[jj * 4 + 2] * invl, acc[jj * 4 + 3] * invl};
    *(float4*)&O[(size_t)(q0 + qi) * C_DIM + h * DHEAD + d0 + jj * 4] = ov;
  }
}

// ---------------- orchestration --------------------------------------------
extern "C" void kernel_launch(void* const* d_in, const int* in_sizes, int n_in,
                              void* d_out, int out_size, void* d_ws, size_t ws_size,
                              hipStream_t stream) {
  const float* x     = (const float*)d_in[0];
  const float* e     = (const float*)d_in[1];
  const float* ctx   = (const float*)d_in[2];
  const float* mod   = (const float*)d_in[3];
  const float* sa_wq = (const float*)d_in[4];
  const float* sa_bq = (const float*)d_in[5];
  const float* sa_wk = (const float*)d_in[6];
  const float* sa_bk = (const float*)d_in[7];
  const float* sa_wv = (const float*)d_in[8];
  const float* sa_bv = (const float*)d_in[9];
  const float* sa_wo = (const float*)d_in[10];
  const float* sa_bo = (const float*)d_in[11];
  const float* sa_nq = (const float*)d_in[12];
  const float* sa_nk = (const float*)d_in[13];
  const float* n3_w  = (const float*)d_in[14];
  const float* n3_b  = (const float*)d_in[15];
  const float* ca_wq = (const float*)d_in[16];
  const float* ca_bq = (const float*)d_in[17];
  const float* ca_wk = (const float*)d_in[18];
  const float* ca_bk = (const float*)d_in[19];
  const float* ca_wv = (const float*)d_in[20];
  const float* ca_bv = (const float*)d_in[21];
  const float* ca_wo = (const float*)d_in[22];
  const float* ca_bo = (const float*)d_in[23];
  const float* ca_nq = (const float*)d_in[24];
  const float* ca_nk = (const float*)d_in[25];
  const float* ffn_w1 = (const float*)d_in[26];
  const float* ffn_b1 = (const float*)d_in[27];
  const float* ffn_w2 = (const float*)d_in[28];
  const float* ffn_b2 = (const float*)d_in[29];
  float* out = (float*)d_out;

  float* ws = (float*)d_ws;
  float* em   = ws; ws += 6 * C_DIM;
  float* cosb = ws; ws += L_SEQ * 64;
  float* sinb = ws; ws += L_SEQ * 64;
  float* xa   = ws; ws += (size_t)L_SEQ * C_DIM;  // xa / y / attn2 scratch
  float* qb   = ws; ws += (size_t)L_SEQ * C_DIM;
  float* kb   = ws; ws += (size_t)L_SEQ * C_DIM;
  float* vb   = ws; ws += (size_t)L_SEQ * C_DIM;
  float* ab   = ws; ws += (size_t)L_SEQ * C_DIM;  // attn out / xc / y2
  float* x1b  = ws; ws += (size_t)L_SEQ * C_DIM;  // x after self-attn / xf
  float* ffnh = ws; ws += (size_t)FFN_CHUNK * FFN_DIM;

  const int nv = L_SEQ * C_DIM;
  dim3 gLC(C_DIM / 64, L_SEQ / 64);
  dim3 gCtx(C_DIM / 64, L_CTX / 64);
  dim3 gAtt(L_SEQ / 32, NHEAD);

  // em = e + mod
  add_kernel<<<(6 * C_DIM) / 256, 256, 0, stream>>>(em, e, mod, 6 * C_DIM);
  rope_tables_kernel<<<L_SEQ, 64, 0, stream>>>(cosb, sinb);

  // ---- self attention ----
  ln_affine_kernel<<<L_SEQ, 256, 0, stream>>>(xa, x, em + C_DIM, em, 1.f);
  gemm_kernel<0><<<gLC, 256, 0, stream>>>(xa, sa_wq, sa_bq, qb, L_SEQ, C_DIM, C_DIM);
  rms_kernel<<<L_SEQ, 256, 0, stream>>>(qb, sa_nq, 0);
  rope_apply_kernel<<<L_SEQ, 256, 0, stream>>>(qb, cosb, sinb);
  gemm_kernel<0><<<gLC, 256, 0, stream>>>(xa, sa_wk, sa_bk, kb, L_SEQ, C_DIM, C_DIM);
  rms_kernel<<<L_SEQ, 256, 0, stream>>>(kb, sa_nk, 0);
  rope_apply_kernel<<<L_SEQ, 256, 0, stream>>>(kb, cosb, sinb);
  gemm_kernel<0><<<gLC, 256, 0, stream>>>(xa, sa_wv, sa_bv, vb, L_SEQ, C_DIM, C_DIM);
  attn_kernel<<<gAtt, 256, 0, stream>>>(qb, kb, vb, ab, L_SEQ);
  gemm_kernel<0><<<gLC, 256, 0, stream>>>(ab, sa_wo, sa_bo, xa, L_SEQ, C_DIM, C_DIM);
  resid_gate_kernel<<<nv / 1024, 256, 0, stream>>>(x1b, x, xa, em + 2 * C_DIM, nv);

  // ---- cross attention ----
  ln_affine_kernel<<<L_SEQ, 256, 0, stream>>>(ab, x1b, n3_w, n3_b, 0.f);
  gemm_kernel<0><<<gLC, 256, 0, stream>>>(ab, ca_wq, ca_bq, qb, L_SEQ, C_DIM, C_DIM);
  rms_kernel<<<L_SEQ, 256, 0, stream>>>(qb, ca_nq, 0);
  gemm_kernel<0><<<gCtx, 256, 0, stream>>>(ctx, ca_wk, ca_bk, kb, L_CTX, C_DIM, C_DIM);
  rms_kernel<<<L_CTX, 256, 0, stream>>>(kb, ca_nk, 0);
  gemm_kernel<0><<<gCtx, 256, 0, stream>>>(ctx, ca_wv, ca_bv, vb, L_CTX, C_DIM, C_DIM);
  attn_kernel<<<gAtt, 256, 0, stream>>>(qb, kb, vb, xa, L_CTX);
  gemm_kernel<0><<<gLC, 256, 0, stream>>>(xa, ca_wo, ca_bo, ab, L_SEQ, C_DIM, C_DIM);
  resid_kernel<<<nv / 1024, 256, 0, stream>>>(out, x1b, ab, nv);

  // ---- FFN ----
  ln_affine_kernel<<<L_SEQ, 256, 0, stream>>>(x1b, out, em + 4 * C_DIM, em + 3 * C_DIM, 1.f);
  for (int c = 0; c < 3; ++c) {
    int r0 = c * FFN_CHUNK;
    dim3 g1(FFN_DIM / 64, FFN_CHUNK / 64);
    gemm_kernel<1><<<g1, 256, 0, stream>>>(x1b + (size_t)r0 * C_DIM, ffn_w1, ffn_b1,
                                           ffnh, FFN_CHUNK, FFN_DIM, C_DIM);
    dim3 g2(C_DIM / 64, FFN_CHUNK / 64);
    gemm_kernel<0><<<g2, 256, 0, stream>>>(ffnh, ffn_w2, ffn_b2,
                                           xa + (size_t)r0 * C_DIM, FFN_CHUNK, C_DIM, FFN_DIM);
  }
  resid_gate_kernel<<<nv / 1024, 256, 0, stream>>>(out, out, xa, em + 5 * C_DIM, nv);
}

// Round 2
// 5373.607 us; speedup vs baseline: 1.6707x; 1.6707x over previous
//
#include <hip/hip_runtime.h>
#include <math.h>

// WanModel transformer block. Round 2: bf16 MFMA GEMMs (m97-style 128x128
// tile, 16x16x32 bf16 MFMA, global_load_lds width-16 staging), fp32 flash
// attention with bank-conflict-free 136-word LDS stride.
// L=4032 (pad 4096), C=1536, NH=12, D=128, L2=512, FFN=8960.

#define L_SEQ 4032
#define L_PAD 4096
#define C_DIM 1536
#define L_CTX 512
#define FFN_DIM 8960
#define NHEAD 12
#define DHEAD 128
#define FFN_CH 2016   // 2 chunks of 2016 rows, padded to 2048
#define FFN_CHP 2048

typedef __attribute__((ext_vector_type(8))) short short8;
typedef __attribute__((ext_vector_type(4))) float floatx4;

__device__ inline unsigned short f2bf(float x) {  // RNE f32 -> bf16
  unsigned int u = __float_as_uint(x);
  u += 0x7fffu + ((u >> 16) & 1u);
  return (unsigned short)(u >> 16);
}

// ---------------- block-wide reduction (256 threads = 4 waves) --------------
__device__ inline float2 block_sum2(float2 v) {
  __shared__ float2 red[4];
#pragma unroll
  for (int o = 32; o > 0; o >>= 1) {
    v.x += __shfl_xor(v.x, o, 64);
    v.y += __shfl_xor(v.y, o, 64);
  }
  int wave = threadIdx.x >> 6;
  if ((threadIdx.x & 63) == 0) red[wave] = v;
  __syncthreads();
  float2 t = make_float2(0.f, 0.f);
#pragma unroll
  for (int i = 0; i < 4; ++i) { t.x += red[i].x; t.y += red[i].y; }
  return t;
}

// ---------------- small elementwise kernels --------------------------------
__global__ void add_kernel(float* __restrict__ o, const float* __restrict__ a,
                           const float* __restrict__ b, int n) {
  int i = blockIdx.x * 256 + threadIdx.x;
  if (i < n) o[i] = a[i] + b[i];
}

__global__ void resid_gate_kernel(float* __restrict__ o, const float* __restrict__ x,
                                  const float* __restrict__ y, const float* __restrict__ g,
                                  int n) {
  int i = (blockIdx.x * 256 + threadIdx.x) * 4;
  if (i < n) {
    float4 xv = *(const float4*)&x[i];
    float4 yv = *(const float4*)&y[i];
    float4 gv = *(const float4*)&g[i % C_DIM];
    float4 ov;
    ov.x = xv.x + yv.x * gv.x;
    ov.y = xv.y + yv.y * gv.y;
    ov.z = xv.z + yv.z * gv.z;
    ov.w = xv.w + yv.w * gv.w;
    *(float4*)&o[i] = ov;
  }
}

__global__ void resid_kernel(float* __restrict__ o, const float* __restrict__ x,
                             const float* __restrict__ y, int n) {
  int i = (blockIdx.x * 256 + threadIdx.x) * 4;
  if (i < n) {
    float4 xv = *(const float4*)&x[i];
    float4 yv = *(const float4*)&y[i];
    float4 ov;
    ov.x = xv.x + yv.x; ov.y = xv.y + yv.y; ov.z = xv.z + yv.z; ov.w = xv.w + yv.w;
    *(float4*)&o[i] = ov;
  }
}

__global__ void f32_to_bf16_kernel(unsigned short* __restrict__ o,
                                   const float* __restrict__ in, int n) {
  int i = (blockIdx.x * 256 + threadIdx.x) * 4;
  if (i < n) {
    float4 v = *(const float4*)&in[i];
    ushort4 o4 = {f2bf(v.x), f2bf(v.y), f2bf(v.z), f2bf(v.w)};
    *(ushort4*)&o[i] = o4;
  }
}

// W (K x N fp32, row-major) -> WT (N x K bf16, row-major)
__global__ __launch_bounds__(256) void transpose_bf16_kernel(
    const float* __restrict__ W, unsigned short* __restrict__ WT, int K, int N) {
  __shared__ float t[32][33];
  int n0 = blockIdx.x * 32, k0 = blockIdx.y * 32;
  int c = threadIdx.x & 31, r0 = threadIdx.x >> 5;
#pragma unroll
  for (int i = 0; i < 4; ++i) {
    int r = r0 + 8 * i;
    t[r][c] = W[(size_t)(k0 + r) * N + n0 + c];
  }
  __syncthreads();
#pragma unroll
  for (int i = 0; i < 4; ++i) {
    int r = r0 + 8 * i;
    WT[(size_t)(n0 + r) * K + k0 + c] = f2bf(t[c][r]);
  }
}

// ---------------- LayerNorm with affine, bf16 output -----------------------
__global__ __launch_bounds__(256) void ln_affine_kernel(
    unsigned short* __restrict__ out, const float* __restrict__ in,
    const float* __restrict__ sc, const float* __restrict__ sh, float addOne) {
  int row = blockIdx.x;
  const float* xr = in + (size_t)row * C_DIM;
  float vals[C_DIM / 256];
  float2 p = make_float2(0.f, 0.f);
  int cnt = 0;
  for (int c = threadIdx.x; c < C_DIM; c += 256) {
    float v = xr[c];
    vals[cnt++] = v;
    p.x += v; p.y += v * v;
  }
  float2 t = block_sum2(p);
  float mean = t.x * (1.f / C_DIM);
  float var = t.y * (1.f / C_DIM) - mean * mean;
  float r = rsqrtf(var + 1e-6f);
  cnt = 0;
  for (int c = threadIdx.x; c < C_DIM; c += 256) {
    float xh = (vals[cnt++] - mean) * r;
    out[(size_t)row * C_DIM + c] = f2bf(xh * (addOne + sc[c]) + sh[c]);
  }
}

// ---------------- RMS norm over full C, fp32 in-place ----------------------
__global__ __launch_bounds__(256) void rms_kernel(float* io, const float* __restrict__ w) {
  int row = blockIdx.x;
  float* xr = io + (size_t)row * C_DIM;
  float vals[C_DIM / 256];
  float s2 = 0.f;
  int cnt = 0;
  for (int c = threadIdx.x; c < C_DIM; c += 256) {
    float v = xr[c];
    vals[cnt++] = v;
    s2 += v * v;
  }
  float2 t = block_sum2(make_float2(s2, 0.f));
  float r = rsqrtf(t.x * (1.f / C_DIM) + 1e-6f);
  cnt = 0;
  for (int c = threadIdx.x; c < C_DIM; c += 256) {
    xr[c] = vals[cnt++] * r * w[c];
  }
}

// ---------------- RoPE -----------------------------------------------------
__global__ void rope_tables_kernel(float* __restrict__ cosb, float* __restrict__ sinb) {
  int l = blockIdx.x, j = threadIdx.x;  // 64 threads
  int f = l / (16 * 28);
  int rem = l % (16 * 28);
  int hh = rem / 28, ww = rem % 28;
  double inv = pow(10000.0, -(double)(2 * j) / 128.0);
  double pos = (j < 22) ? (double)f : ((j < 43) ? (double)hh : (double)ww);
  double ang = pos * inv;
  cosb[l * 64 + j] = (float)cos(ang);
  sinb[l * 64 + j] = (float)sin(ang);
}

__global__ void rope_apply_kernel(float* __restrict__ x, const float* __restrict__ cosb,
                                  const float* __restrict__ sinb) {
  int l = blockIdx.x;
  for (int t = threadIdx.x; t < NHEAD * 64; t += 256) {
    int n = t >> 6, j = t & 63;
    float co = cosb[l * 64 + j], si = sinb[l * 64 + j];
    float* p = x + (size_t)l * C_DIM + n * DHEAD + 2 * j;
    float x0 = p[0], x1 = p[1];
    p[0] = x0 * co - x1 * si;
    p[1] = x0 * si + x1 * co;
  }
}

// ---------------- bf16 MFMA GEMM -------------------------------------------
// C[m][n] = sum_k A[m][k]*BT[n][k] + bias[n].  A: bf16 (Mpad x K), BT: bf16
// (N x K), both row-major.  N%128==0, K%32==0.  Block 256 = 4 waves, tile
// 128x128, each wave 64x64 (4x4 MFMA tiles of 16x16x32).
// LDS layout (fragment order): chunk c = g*64 + q*16 + m holds
// A[row0+g*16+m][k0+q*8 .. +7]  (16 bytes).  global_load_lds dest = wave-
// uniform base + lane*16 matches chunks base+lane.
// EPI: 0 = fp32 out, 1 = tanh-gelu + bf16 out.
__device__ inline float gelu_tanh(float x) {
  float x3 = x * x * x;
  return 0.5f * x * (1.f + tanhf(0.79788456080286535588f * (x + 0.044715f * x3)));
}

template <int EPI>
__global__ __launch_bounds__(256) void mgemm_kernel(
    const unsigned short* __restrict__ A, const unsigned short* __restrict__ BT,
    const float* __restrict__ bias, void* __restrict__ Cout,
    int N, int K, int Mlimit) {
  __shared__ short sA[4096];  // 128 x 32 bf16, fragment order
  __shared__ short sB[4096];
  const int tid = threadIdx.x;
  const int wv = tid >> 6, lane = tid & 63;
  const int lm = lane & 15, lq = lane >> 4;
  const int wr = wv >> 1, wc = wv & 1;
  const int row0 = blockIdx.y * 128, col0 = blockIdx.x * 128;

  floatx4 zero4 = {0.f, 0.f, 0.f, 0.f};
  floatx4 acc[4][4];
#pragma unroll
  for (int i = 0; i < 4; ++i)
#pragma unroll
    for (int j = 0; j < 4; ++j) acc[i][j] = zero4;

  const unsigned short* Abase = A + (size_t)row0 * K + (size_t)(lm)*K + lq * 8;
  const unsigned short* Bbase = BT + (size_t)col0 * K + (size_t)(lm)*K + lq * 8;

  for (int k0 = 0; k0 < K; k0 += 32) {
    __syncthreads();
#pragma unroll
    for (int t = 0; t < 2; ++t) {
      int g = wv * 2 + t;
      const unsigned short* gpa = Abase + (size_t)(g * 16) * K + k0;
      const unsigned short* gpb = Bbase + (size_t)(g * 16) * K + k0;
      __builtin_amdgcn_global_load_lds(
          (const __attribute__((address_space(1))) void*)gpa,
          (__attribute__((address_space(3))) void*)(sA + g * 512), 16, 0, 0);
      __builtin_amdgcn_global_load_lds(
          (const __attribute__((address_space(1))) void*)gpb,
          (__attribute__((address_space(3))) void*)(sB + g * 512), 16, 0, 0);
    }
    __syncthreads();
    short8 af[4], bfv[4];
#pragma unroll
    for (int mt = 0; mt < 4; ++mt)
      af[mt] = *(const short8*)(sA + (wr * 4 + mt) * 512 + lq * 128 + lm * 8);
#pragma unroll
    for (int nt = 0; nt < 4; ++nt)
      bfv[nt] = *(const short8*)(sB + (wc * 4 + nt) * 512 + lq * 128 + lm * 8);
#pragma unroll
    for (int mt = 0; mt < 4; ++mt)
#pragma unroll
      for (int nt = 0; nt < 4; ++nt)
        acc[mt][nt] = __builtin_amdgcn_mfma_f32_16x16x32_bf16(
            af[mt], bfv[nt], acc[mt][nt], 0, 0, 0);
  }

  // epilogue: C/D layout col = lane&15, row = (lane>>4)*4 + reg
#pragma unroll
  for (int nt = 0; nt < 4; ++nt) {
    int colg = col0 + wc * 64 + nt * 16 + lm;
    float bv = bias[colg];
#pragma unroll
    for (int mt = 0; mt < 4; ++mt) {
#pragma unroll
      for (int r = 0; r < 4; ++r) {
        int rowg = row0 + wr * 64 + mt * 16 + lq * 4 + r;
        if (rowg < Mlimit) {
          float v = acc[mt][nt][r] + bv;
          if (EPI == 1) {
            ((unsigned short*)Cout)[(size_t)rowg * N + colg] = f2bf(gelu_tanh(v));
          } else {
            ((float*)Cout)[(size_t)rowg * N + colg] = v;
          }
        }
      }
    }
  }
}

// ---------------- fp32 flash attention, bf16 output ------------------------
// Q,K,V: (rows, C_DIM) fp32, head h at cols [h*128, h*128+128).
// O: (rows, C_DIM) bf16.  Grid: (Lq/32, NHEAD).  Block 256.
// LDS row stride 136 words (136%32==8): the 8 distinct K-row float4 reads per
// wave land on bank starts {0,8,16,24}x2 -> 2-way (free) instead of ~8-way.
__global__ __launch_bounds__(256) void attn_kernel(
    const float* __restrict__ Q, const float* __restrict__ Kb,
    const float* __restrict__ Vb, unsigned short* __restrict__ O, int Lk) {
  const int h = blockIdx.y;
  const int q0 = blockIdx.x * 32;
  const int tid = threadIdx.x;
  __shared__ float Qs[32][136];
  __shared__ float Ks[32][136];
  __shared__ float Vs[32][136];
  const float scale = 0.08838834764831845f;  // 1/sqrt(128)

#pragma unroll
  for (int i = 0; i < 4; ++i) {
    int idx = tid * 16 + i * 4;
    int r = idx >> 7, c = idx & 127;
    float4 v = *(const float4*)&Q[(size_t)(q0 + r) * C_DIM + h * DHEAD + c];
    v.x *= scale; v.y *= scale; v.z *= scale; v.w *= scale;
    *(float4*)&Qs[r][c] = v;
  }
  const int qi = tid >> 3;
  const int g8 = tid & 7;
  const int d0 = g8 << 4;
  float acc[16];
#pragma unroll
  for (int j = 0; j < 16; ++j) acc[j] = 0.f;
  float m_reg = -1e30f, l_reg = 0.f;

  for (int k0 = 0; k0 < Lk; k0 += 32) {
    __syncthreads();
#pragma unroll
    for (int i = 0; i < 4; ++i) {
      int idx = tid * 16 + i * 4;
      int r = idx >> 7, c = idx & 127;
      *(float4*)&Ks[r][c] = *(const float4*)&Kb[(size_t)(k0 + r) * C_DIM + h * DHEAD + c];
      *(float4*)&Vs[r][c] = *(const float4*)&Vb[(size_t)(k0 + r) * C_DIM + h * DHEAD + c];
    }
    __syncthreads();
    float s[4] = {0.f, 0.f, 0.f, 0.f};
#pragma unroll
    for (int dd = 0; dd < 32; ++dd) {
      float4 q4 = *(const float4*)&Qs[qi][dd << 2];
#pragma unroll
      for (int i = 0; i < 4; ++i) {
        float4 k4 = *(const float4*)&Ks[g8 + (i << 3)][dd << 2];
        s[i] += q4.x * k4.x + q4.y * k4.y + q4.z * k4.z + q4.w * k4.w;
      }
    }
    float lmax = fmaxf(fmaxf(s[0], s[1]), fmaxf(s[2], s[3]));
#pragma unroll
    for (int o = 1; o < 8; o <<= 1) lmax = fmaxf(lmax, __shfl_xor(lmax, o, 8));
    float m_new = fmaxf(m_reg, lmax);
    float alpha = expf(m_reg - m_new);
    float p[4], ps = 0.f;
#pragma unroll
    for (int i = 0; i < 4; ++i) { p[i] = expf(s[i] - m_new); ps += p[i]; }
#pragma unroll
    for (int o = 1; o < 8; o <<= 1) ps += __shfl_xor(ps, o, 8);
    l_reg = l_reg * alpha + ps;
    m_reg = m_new;
#pragma unroll
    for (int j = 0; j < 16; ++j) acc[j] *= alpha;
#pragma unroll
    for (int i = 0; i < 4; ++i) {
#pragma unroll
      for (int g = 0; g < 8; ++g) {
        int kj = (i << 3) + g;
        float pk = __shfl(p[i], g, 8);
        float4 v0 = *(const float4*)&Vs[kj][d0];
        float4 v1 = *(const float4*)&Vs[kj][d0 + 4];
        float4 v2 = *(const float4*)&Vs[kj][d0 + 8];
        float4 v3 = *(const float4*)&Vs[kj][d0 + 12];
        acc[0]  = fmaf(pk, v0.x, acc[0]);  acc[1]  = fmaf(pk, v0.y, acc[1]);
        acc[2]  = fmaf(pk, v0.z, acc[2]);  acc[3]  = fmaf(pk, v0.w, acc[3]);
        acc[4]  = fmaf(pk, v1.x, acc[4]);  acc[5]  = fmaf(pk, v1.y, acc[5]);
        acc[6]  = fmaf(pk, v1.z, acc[6]);  acc[7]  = fmaf(pk, v1.w, acc[7]);
        acc[8]  = fmaf(pk, v2.x, acc[8]);  acc[9]  = fmaf(pk, v2.y, acc[9]);
        acc[10] = fmaf(pk, v2.z, acc[10]); acc[11] = fmaf(pk, v2.w, acc[11]);
        acc[12] = fmaf(pk, v3.x, acc[12]); acc[13] = fmaf(pk, v3.y, acc[13]);
        acc[14] = fmaf(pk, v3.z, acc[14]); acc[15] = fmaf(pk, v3.w, acc[15]);
      }
    }
  }
  float invl = 1.f / l_reg;
#pragma unroll
  for (int jj = 0; jj < 4; ++jj) {
    ushort4 ov = {f2bf(acc[jj * 4 + 0] * invl), f2bf(acc[jj * 4 + 1] * invl),
                  f2bf(acc[jj * 4 + 2] * invl), f2bf(acc[jj * 4 + 3] * invl)};
    *(ushort4*)&O[(size_t)(q0 + qi) * C_DIM + h * DHEAD + d0 + jj * 4] = ov;
  }
}

// ---------------- orchestration --------------------------------------------
extern "C" void kernel_launch(void* const* d_in, const int* in_sizes, int n_in,
                              void* d_out, int out_size, void* d_ws, size_t ws_size,
                              hipStream_t stream) {
  const float* x     = (const float*)d_in[0];
  const float* e     = (const float*)d_in[1];
  const float* ctx   = (const float*)d_in[2];
  const float* mod   = (const float*)d_in[3];
  const float* sa_wq = (const float*)d_in[4];
  const float* sa_bq = (const float*)d_in[5];
  const float* sa_wk = (const float*)d_in[6];
  const float* sa_bk = (const float*)d_in[7];
  const float* sa_wv = (const float*)d_in[8];
  const float* sa_bv = (const float*)d_in[9];
  const float* sa_wo = (const float*)d_in[10];
  const float* sa_bo = (const float*)d_in[11];
  const float* sa_nq = (const float*)d_in[12];
  const float* sa_nk = (const float*)d_in[13];
  const float* n3_w  = (const float*)d_in[14];
  const float* n3_b  = (const float*)d_in[15];
  const float* ca_wq = (const float*)d_in[16];
  const float* ca_bq = (const float*)d_in[17];
  const float* ca_wk = (const float*)d_in[18];
  const float* ca_bk = (const float*)d_in[19];
  const float* ca_wv = (const float*)d_in[20];
  const float* ca_bv = (const float*)d_in[21];
  const float* ca_wo = (const float*)d_in[22];
  const float* ca_bo = (const float*)d_in[23];
  const float* ca_nq = (const float*)d_in[24];
  const float* ca_nk = (const float*)d_in[25];
  const float* ffn_w1 = (const float*)d_in[26];
  const float* ffn_b1 = (const float*)d_in[27];
  const float* ffn_w2 = (const float*)d_in[28];
  const float* ffn_b2 = (const float*)d_in[29];
  float* out = (float*)d_out;

  char* wsb = (char*)d_ws;
  auto alloc_f = [&](size_t n) { float* p = (float*)wsb; wsb += ((n * 4 + 255) / 256) * 256; return p; };
  auto alloc_h = [&](size_t n) { unsigned short* p = (unsigned short*)wsb; wsb += ((n * 2 + 255) / 256) * 256; return p; };

  float* em   = alloc_f(6 * C_DIM);
  float* cosb = alloc_f(L_SEQ * 64);
  float* sinb = alloc_f(L_SEQ * 64);
  float* qb   = alloc_f((size_t)L_SEQ * C_DIM);
  float* kb   = alloc_f((size_t)L_SEQ * C_DIM);
  float* vb   = alloc_f((size_t)L_SEQ * C_DIM);  // also GEMM y-outputs (see order)
  float* x1b  = alloc_f((size_t)L_SEQ * C_DIM);
  unsigned short* act_bf  = alloc_h((size_t)L_PAD * C_DIM);
  unsigned short* ctx_bf  = alloc_h((size_t)L_CTX * C_DIM);
  unsigned short* ffnh_bf = alloc_h((size_t)FFN_CHP * FFN_DIM);
  unsigned short* wtq = alloc_h((size_t)C_DIM * C_DIM);
  unsigned short* wtk = alloc_h((size_t)C_DIM * C_DIM);
  unsigned short* wtv = alloc_h((size_t)C_DIM * C_DIM);
  unsigned short* wto = alloc_h((size_t)C_DIM * C_DIM);
  unsigned short* wtcq = alloc_h((size_t)C_DIM * C_DIM);
  unsigned short* wtck = alloc_h((size_t)C_DIM * C_DIM);
  unsigned short* wtcv = alloc_h((size_t)C_DIM * C_DIM);
  unsigned short* wtco = alloc_h((size_t)C_DIM * C_DIM);
  unsigned short* wt1  = alloc_h((size_t)FFN_DIM * C_DIM);  // (8960 x 1536)
  unsigned short* wt2  = alloc_h((size_t)C_DIM * FFN_DIM);  // (1536 x 8960)

  const int nv = L_SEQ * C_DIM;
  dim3 gT(C_DIM / 32, C_DIM / 32);
  dim3 gGL(C_DIM / 128, L_PAD / 128);     // (12, 32)
  dim3 gGC(C_DIM / 128, L_CTX / 128);     // (12, 4)
  dim3 gAtt(L_SEQ / 32, NHEAD);

  // weight transposes + converts (per call; ~45 us total)
  transpose_bf16_kernel<<<gT, 256, 0, stream>>>(sa_wq, wtq, C_DIM, C_DIM);
  transpose_bf16_kernel<<<gT, 256, 0, stream>>>(sa_wk, wtk, C_DIM, C_DIM);
  transpose_bf16_kernel<<<gT, 256, 0, stream>>>(sa_wv, wtv, C_DIM, C_DIM);
  transpose_bf16_kernel<<<gT, 256, 0, stream>>>(sa_wo, wto, C_DIM, C_DIM);
  transpose_bf16_kernel<<<gT, 256, 0, stream>>>(ca_wq, wtcq, C_DIM, C_DIM);
  transpose_bf16_kernel<<<gT, 256, 0, stream>>>(ca_wk, wtck, C_DIM, C_DIM);
  transpose_bf16_kernel<<<gT, 256, 0, stream>>>(ca_wv, wtcv, C_DIM, C_DIM);
  transpose_bf16_kernel<<<gT, 256, 0, stream>>>(ca_wo, wtco, C_DIM, C_DIM);
  transpose_bf16_kernel<<<dim3(FFN_DIM / 32, C_DIM / 32), 256, 0, stream>>>(ffn_w1, wt1, C_DIM, FFN_DIM);
  transpose_bf16_kernel<<<dim3(C_DIM / 32, FFN_DIM / 32), 256, 0, stream>>>(ffn_w2, wt2, FFN_DIM, C_DIM);
  f32_to_bf16_kernel<<<(L_CTX * C_DIM) / 1024, 256, 0, stream>>>(ctx_bf, ctx, L_CTX * C_DIM);

  add_kernel<<<(6 * C_DIM + 255) / 256, 256, 0, stream>>>(em, e, mod, 6 * C_DIM);
  rope_tables_kernel<<<L_SEQ, 64, 0, stream>>>(cosb, sinb);

  // ---- self attention ----
  ln_affine_kernel<<<L_SEQ, 256, 0, stream>>>(act_bf, x, em + C_DIM, em, 1.f);
  mgemm_kernel<0><<<gGL, 256, 0, stream>>>(act_bf, wtq, sa_bq, qb, C_DIM, C_DIM, L_SEQ);
  rms_kernel<<<L_SEQ, 256, 0, stream>>>(qb, sa_nq);
  rope_apply_kernel<<<L_SEQ, 256, 0, stream>>>(qb, cosb, sinb);
  mgemm_kernel<0><<<gGL, 256, 0, stream>>>(act_bf, wtk, sa_bk, kb, C_DIM, C_DIM, L_SEQ);
  rms_kernel<<<L_SEQ, 256, 0, stream>>>(kb, sa_nk);
  rope_apply_kernel<<<L_SEQ, 256, 0, stream>>>(kb, cosb, sinb);
  mgemm_kernel<0><<<gGL, 256, 0, stream>>>(act_bf, wtv, sa_bv, vb, C_DIM, C_DIM, L_SEQ);
  attn_kernel<<<gAtt, 256, 0, stream>>>(qb, kb, vb, act_bf, L_SEQ);
  mgemm_kernel<0><<<gGL, 256, 0, stream>>>(act_bf, wto, sa_bo, vb, C_DIM, C_DIM, L_SEQ);
  resid_gate_kernel<<<nv / 1024, 256, 0, stream>>>(x1b, x, vb, em + 2 * C_DIM, nv);

  // ---- cross attention ----
  ln_affine_kernel<<<L_SEQ, 256, 0, stream>>>(act_bf, x1b, n3_w, n3_b, 0.f);
  mgemm_kernel<0><<<gGL, 256, 0, stream>>>(act_bf, wtcq, ca_bq, qb, C_DIM, C_DIM, L_SEQ);
  rms_kernel<<<L_SEQ, 256, 0, stream>>>(qb, ca_nq);
  mgemm_kernel<0><<<gGC, 256, 0, stream>>>(ctx_bf, wtck, ca_bk, kb, C_DIM, C_DIM, L_CTX);
  rms_kernel<<<L_CTX, 256, 0, stream>>>(kb, ca_nk);
  mgemm_kernel<0><<<gGC, 256, 0, stream>>>(ctx_bf, wtcv, ca_bv, vb, C_DIM, C_DIM, L_CTX);
  attn_kernel<<<gAtt, 256, 0, stream>>>(qb, kb, vb, act_bf, L_CTX);
  mgemm_kernel<0><<<gGL, 256, 0, stream>>>(act_bf, wtco, ca_bo, vb, C_DIM, C_DIM, L_SEQ);
  resid_kernel<<<nv / 1024, 256, 0, stream>>>(out, x1b, vb, nv);

  // ---- FFN (2 row-chunks of 2016, padded to 2048) ----
  ln_affine_kernel<<<L_SEQ, 256, 0, stream>>>(act_bf, out, em + 4 * C_DIM, em + 3 * C_DIM, 1.f);
  for (int c = 0; c < 2; ++c) {
    int mlim = (c == 0) ? FFN_CHP : (L_SEQ - FFN_CH);  // 2048 / 2016
    dim3 g1(FFN_DIM / 128, FFN_CHP / 128);  // (70, 16)
    mgemm_kernel<1><<<g1, 256, 0, stream>>>(act_bf + (size_t)c * FFN_CH * C_DIM, wt1,
                                            ffn_b1, ffnh_bf, FFN_DIM, C_DIM, mlim);
    dim3 g2(C_DIM / 128, FFN_CHP / 128);    // (12, 16)
    mgemm_kernel<0><<<g2, 256, 0, stream>>>(ffnh_bf, wt2, ffn_b2,
                                            vb + (size_t)c * FFN_CH * C_DIM, C_DIM, FFN_DIM, mlim);
  }
  resid_gate_kernel<<<nv / 1024, 256, 0, stream>>>(out, out, vb, em + 5 * C_DIM, nv);
}